// Round 2
// baseline (453.436 us; speedup 1.0000x reference)
//
#include <hip/hip_runtime.h>
#include <hip/hip_cooperative_groups.h>

#define B_ROWS 16384
#define FEAT   2048
#define MARGIN 1.0f

#define NBLK   1024                 // cooperative grid: 4 blocks/CU x 256 CU
#define WPB    4                    // waves per block
#define RPW    4                    // rows per wave  (1024*4*4 = 16384 rows)

typedef float vfloat4 __attribute__((ext_vector_type(4)));

namespace cg = cooperative_groups;

// Fused: persistent cooperative kernel.
// Phase 1: each wave computes RPW contiguous rows' triplet losses
//          (two half-row register batches of 4 float4 per stream -> 48 data
//           VGPRs in flight, fits the __launch_bounds__(256,4) 128-VGPR cap).
// Phase 2: grid.sync(); block 0 reduces the 1024 per-block partials.
__global__ __launch_bounds__(256, 4) void TripletLoss_90091234001212_kernel(
    const float* __restrict__ anc,
    const float* __restrict__ pos,
    const float* __restrict__ neg,
    float* __restrict__ ws,
    float* __restrict__ out)
{
    const int tid  = threadIdx.x;
    const int lane = tid & 63;
    const int wave = tid >> 6;

    float wl = 0.0f;  // per-wave loss accumulator (meaningful on lane 0)

    const int row0 = blockIdx.x * (WPB * RPW) + wave * RPW;
    #pragma unroll
    for (int r = 0; r < RPW; ++r) {
        const int row = row0 + r;
        const vfloat4* a4 = (const vfloat4*)(anc + (size_t)row * FEAT);
        const vfloat4* p4 = (const vfloat4*)(pos + (size_t)row * FEAT);
        const vfloat4* n4 = (const vfloat4*)(neg + (size_t)row * FEAT);

        float dp = 0.0f, dn = 0.0f;
        #pragma unroll
        for (int h = 0; h < 2; ++h) {
            const int base = lane + h * 256;   // float4 index within the row
            vfloat4 a[4], p[4], n[4];
            #pragma unroll
            for (int k = 0; k < 4; ++k) a[k] = __builtin_nontemporal_load(&a4[base + 64 * k]);
            #pragma unroll
            for (int k = 0; k < 4; ++k) p[k] = __builtin_nontemporal_load(&p4[base + 64 * k]);
            #pragma unroll
            for (int k = 0; k < 4; ++k) n[k] = __builtin_nontemporal_load(&n4[base + 64 * k]);

            #pragma unroll
            for (int k = 0; k < 4; ++k) {
                float d;
                d = a[k].x - p[k].x; dp += d * d;
                d = a[k].y - p[k].y; dp += d * d;
                d = a[k].z - p[k].z; dp += d * d;
                d = a[k].w - p[k].w; dp += d * d;
                d = a[k].x - n[k].x; dn += d * d;
                d = a[k].y - n[k].y; dn += d * d;
                d = a[k].z - n[k].z; dn += d * d;
                d = a[k].w - n[k].w; dn += d * d;
            }
        }

        #pragma unroll
        for (int off = 32; off > 0; off >>= 1) {
            dp += __shfl_down(dp, off);
            dn += __shfl_down(dn, off);
        }
        if (lane == 0)
            wl += fmaxf(sqrtf(dp) - sqrtf(dn) + MARGIN, 0.0f);
    }

    __shared__ float sl[WPB];
    if (lane == 0) sl[wave] = wl;
    __syncthreads();
    if (tid == 0)
        ws[blockIdx.x] = (sl[0] + sl[1]) + (sl[2] + sl[3]);

    cg::this_grid().sync();

    if (blockIdx.x == 0) {
        // 1024 partials = 256 x one float4
        const vfloat4 v = ((const vfloat4*)ws)[tid];
        float s = (v.x + v.y) + (v.z + v.w);
        #pragma unroll
        for (int off = 32; off > 0; off >>= 1)
            s += __shfl_down(s, off);

        __shared__ float part[4];
        if (lane == 0) part[wave] = s;
        __syncthreads();
        if (tid == 0)
            out[0] = ((part[0] + part[1]) + (part[2] + part[3]))
                     * (1.0f / (float)B_ROWS);
    }
}

// ---- fallback path (two kernels), used only if cooperative launch fails ----
__global__ __launch_bounds__(256) void tl_stage1(
    const float* __restrict__ anc, const float* __restrict__ pos,
    const float* __restrict__ neg, float* __restrict__ ws)
{
    const int tid  = threadIdx.x;
    const int lane = tid & 63;
    const int wave = tid >> 6;
    const int row  = blockIdx.x * 4 + wave;

    const vfloat4* a4 = (const vfloat4*)(anc + (size_t)row * FEAT);
    const vfloat4* p4 = (const vfloat4*)(pos + (size_t)row * FEAT);
    const vfloat4* n4 = (const vfloat4*)(neg + (size_t)row * FEAT);

    float dp = 0.0f, dn = 0.0f;
    #pragma unroll
    for (int h = 0; h < 2; ++h) {
        const int base = lane + h * 256;
        vfloat4 a[4], p[4], n[4];
        #pragma unroll
        for (int k = 0; k < 4; ++k) a[k] = __builtin_nontemporal_load(&a4[base + 64 * k]);
        #pragma unroll
        for (int k = 0; k < 4; ++k) p[k] = __builtin_nontemporal_load(&p4[base + 64 * k]);
        #pragma unroll
        for (int k = 0; k < 4; ++k) n[k] = __builtin_nontemporal_load(&n4[base + 64 * k]);
        #pragma unroll
        for (int k = 0; k < 4; ++k) {
            float d;
            d = a[k].x - p[k].x; dp += d * d;
            d = a[k].y - p[k].y; dp += d * d;
            d = a[k].z - p[k].z; dp += d * d;
            d = a[k].w - p[k].w; dp += d * d;
            d = a[k].x - n[k].x; dn += d * d;
            d = a[k].y - n[k].y; dn += d * d;
            d = a[k].z - n[k].z; dn += d * d;
            d = a[k].w - n[k].w; dn += d * d;
        }
    }
    #pragma unroll
    for (int off = 32; off > 0; off >>= 1) {
        dp += __shfl_down(dp, off);
        dn += __shfl_down(dn, off);
    }
    __shared__ float sl[4];
    if (lane == 0)
        sl[wave] = fmaxf(sqrtf(dp) - sqrtf(dn) + MARGIN, 0.0f);
    __syncthreads();
    if (tid == 0) ws[blockIdx.x] = (sl[0] + sl[1]) + (sl[2] + sl[3]);
}

__global__ __launch_bounds__(256) void tl_reduce(
    const float* __restrict__ ws, float* __restrict__ out)
{
    const int tid  = threadIdx.x;
    const int lane = tid & 63;
    const int wave = tid >> 6;
    const vfloat4* w4 = (const vfloat4*)ws;
    float s = 0.0f;
    #pragma unroll
    for (int it = 0; it < 4; ++it) {
        const vfloat4 v = w4[it * 256 + tid];
        s += (v.x + v.y) + (v.z + v.w);
    }
    #pragma unroll
    for (int off = 32; off > 0; off >>= 1)
        s += __shfl_down(s, off);
    __shared__ float partial[4];
    if (lane == 0) partial[wave] = s;
    __syncthreads();
    if (tid == 0)
        out[0] = ((partial[0] + partial[1]) + (partial[2] + partial[3]))
                 * (1.0f / (float)B_ROWS);
}

extern "C" void kernel_launch(void* const* d_in, const int* in_sizes, int n_in,
                              void* d_out, int out_size, void* d_ws, size_t ws_size,
                              hipStream_t stream) {
    const float* anc = (const float*)d_in[0];
    const float* pos = (const float*)d_in[1];
    const float* neg = (const float*)d_in[2];
    float* out = (float*)d_out;
    float* ws  = (float*)d_ws;

    void* args[] = { (void*)&anc, (void*)&pos, (void*)&neg, (void*)&ws, (void*)&out };
    hipError_t err = hipLaunchCooperativeKernel(
        (const void*)TripletLoss_90091234001212_kernel,
        dim3(NBLK), dim3(256), args, 0, stream);

    if (err != hipSuccess) {
        // fallback: classic two-kernel path
        tl_stage1<<<B_ROWS / 4, 256, 0, stream>>>(anc, pos, neg, ws);
        tl_reduce<<<1, 256, 0, stream>>>(ws, out);
    }
}

// Round 4
// 349.819 us; speedup vs baseline: 1.2962x; 1.2962x over previous
//
#include <hip/hip_runtime.h>

#define B_ROWS 16384
#define FEAT   2048
#define MARGIN 1.0f
#define RPB    4                    // rows per block == waves per block
#define NBLK   (B_ROWS / RPB)       // 4096 stage-1 blocks / ws partials

typedef float vfloat4 __attribute__((ext_vector_type(4)));

// Stage 1: one WAVE per row. 2048 floats/row / 64 lanes = 32 floats =
// 8 float4 per lane per stream -> 24 independent 1-KB wave-loads in flight.
// Plain cached loads (NOT nontemporal): rocprof round-2 showed ~50% of the
// 402 MB input stream is served by the Infinity Cache across iterations;
// evict-first NT policy works against that reuse.
__global__ __launch_bounds__(256) void TripletLoss_90091234001212_kernel(
    const float* __restrict__ anc,
    const float* __restrict__ pos,
    const float* __restrict__ neg,
    float* __restrict__ ws)
{
    const int tid  = threadIdx.x;
    const int lane = tid & 63;
    const int wave = tid >> 6;
    const int row  = blockIdx.x * RPB + wave;

    const vfloat4* a4 = (const vfloat4*)(anc + (size_t)row * FEAT);
    const vfloat4* p4 = (const vfloat4*)(pos + (size_t)row * FEAT);
    const vfloat4* n4 = (const vfloat4*)(neg + (size_t)row * FEAT);

    vfloat4 a[8], p[8], n[8];
    #pragma unroll
    for (int k = 0; k < 8; ++k) a[k] = a4[lane + 64 * k];
    #pragma unroll
    for (int k = 0; k < 8; ++k) p[k] = p4[lane + 64 * k];
    #pragma unroll
    for (int k = 0; k < 8; ++k) n[k] = n4[lane + 64 * k];

    float dp = 0.0f, dn = 0.0f;
    #pragma unroll
    for (int k = 0; k < 8; ++k) {
        float d;
        d = a[k].x - p[k].x; dp += d * d;
        d = a[k].y - p[k].y; dp += d * d;
        d = a[k].z - p[k].z; dp += d * d;
        d = a[k].w - p[k].w; dp += d * d;
        d = a[k].x - n[k].x; dn += d * d;
        d = a[k].y - n[k].y; dn += d * d;
        d = a[k].z - n[k].z; dn += d * d;
        d = a[k].w - n[k].w; dn += d * d;
    }

    // wave-64 butterfly reduce (two values, 12 wave-instructions total)
    #pragma unroll
    for (int off = 32; off > 0; off >>= 1) {
        dp += __shfl_down(dp, off);
        dn += __shfl_down(dn, off);
    }

    __shared__ float sl[RPB];
    if (lane == 0)
        sl[wave] = fmaxf(sqrtf(dp) - sqrtf(dn) + MARGIN, 0.0f);
    __syncthreads();

    if (tid == 0)
        ws[blockIdx.x] = (sl[0] + sl[1]) + (sl[2] + sl[3]);
}

// Stage 2: reduce NBLK (=4096) per-block partials -> out[0]. 16 KB read.
__global__ __launch_bounds__(256) void tl_reduce(
    const float* __restrict__ ws, float* __restrict__ out)
{
    const int tid  = threadIdx.x;
    const int lane = tid & 63;
    const int wave = tid >> 6;

    // 4096 floats = 1024 float4; 256 threads x 4 float4
    const vfloat4* w4 = (const vfloat4*)ws;
    float s = 0.0f;
    #pragma unroll
    for (int it = 0; it < 4; ++it) {
        const vfloat4 v = w4[it * 256 + tid];
        s += (v.x + v.y) + (v.z + v.w);
    }

    #pragma unroll
    for (int off = 32; off > 0; off >>= 1)
        s += __shfl_down(s, off);

    __shared__ float partial[4];
    if (lane == 0) partial[wave] = s;
    __syncthreads();

    if (tid == 0)
        out[0] = ((partial[0] + partial[1]) + (partial[2] + partial[3]))
                 * (1.0f / (float)B_ROWS);
}

extern "C" void kernel_launch(void* const* d_in, const int* in_sizes, int n_in,
                              void* d_out, int out_size, void* d_ws, size_t ws_size,
                              hipStream_t stream) {
    const float* anc = (const float*)d_in[0];
    const float* pos = (const float*)d_in[1];
    const float* neg = (const float*)d_in[2];
    float* out = (float*)d_out;
    float* ws  = (float*)d_ws;

    TripletLoss_90091234001212_kernel<<<NBLK, 256, 0, stream>>>(anc, pos, neg, ws);
    tl_reduce<<<1, 256, 0, stream>>>(ws, out);
}

// Round 5
// 317.843 us; speedup vs baseline: 1.4266x; 1.1006x over previous
//
#include <hip/hip_runtime.h>

#define B_ROWS 16384
#define FEAT   2048
#define MARGIN 1.0f

typedef float vfloat4 __attribute__((ext_vector_type(4)));

// Stage 1: one block (256 thr) per row; 2 float4 per thread per stream.
// NT loads are REQUIRED: round-4 A/B showed plain cached loads collapse MLP
// (compiler interleaves load-use, 44 VGPR, vmcnt-serialized -> 130 us,
// duration invariant to FETCH_SIZE = latency-bound). The NT builtin keeps
// all 6 16B loads in flight up front (56 VGPR, stage-1 ~75 us).
// FETCH_SIZE evidence (rounds 2/4): MALL serves ~50% regardless of nt bit.
__global__ __launch_bounds__(256) void TripletLoss_90091234001212_kernel(
    const float* __restrict__ anc,
    const float* __restrict__ pos,
    const float* __restrict__ neg,
    float* __restrict__ ws)
{
    const int tid  = threadIdx.x;
    const int lane = tid & 63;
    const int wave = tid >> 6;
    const int row  = blockIdx.x;

    const vfloat4* a4 = (const vfloat4*)(anc + (size_t)row * FEAT);
    const vfloat4* p4 = (const vfloat4*)(pos + (size_t)row * FEAT);
    const vfloat4* n4 = (const vfloat4*)(neg + (size_t)row * FEAT);

    // 512 float4 per row / 256 threads = 2 per thread; 6 independent loads.
    const int i0 = tid;
    const int i1 = tid + 256;
    const vfloat4 a0 = __builtin_nontemporal_load(&a4[i0]);
    const vfloat4 a1 = __builtin_nontemporal_load(&a4[i1]);
    const vfloat4 p0 = __builtin_nontemporal_load(&p4[i0]);
    const vfloat4 p1 = __builtin_nontemporal_load(&p4[i1]);
    const vfloat4 n0 = __builtin_nontemporal_load(&n4[i0]);
    const vfloat4 n1 = __builtin_nontemporal_load(&n4[i1]);

    float dp = 0.0f, dn = 0.0f, d;
    d = a0.x - p0.x; dp += d * d;
    d = a0.y - p0.y; dp += d * d;
    d = a0.z - p0.z; dp += d * d;
    d = a0.w - p0.w; dp += d * d;
    d = a1.x - p1.x; dp += d * d;
    d = a1.y - p1.y; dp += d * d;
    d = a1.z - p1.z; dp += d * d;
    d = a1.w - p1.w; dp += d * d;
    d = a0.x - n0.x; dn += d * d;
    d = a0.y - n0.y; dn += d * d;
    d = a0.z - n0.z; dn += d * d;
    d = a0.w - n0.w; dn += d * d;
    d = a1.x - n1.x; dn += d * d;
    d = a1.y - n1.y; dn += d * d;
    d = a1.z - n1.z; dn += d * d;
    d = a1.w - n1.w; dn += d * d;

    // wave-64 butterfly reduce (two values)
    #pragma unroll
    for (int off = 32; off > 0; off >>= 1) {
        dp += __shfl_down(dp, off);
        dn += __shfl_down(dn, off);
    }

    __shared__ float sdp[4], sdn[4];
    if (lane == 0) { sdp[wave] = dp; sdn[wave] = dn; }
    __syncthreads();

    if (tid == 0) {
        const float tdp = sdp[0] + sdp[1] + sdp[2] + sdp[3];
        const float tdn = sdn[0] + sdn[1] + sdn[2] + sdn[3];
        const float loss = sqrtf(tdp) - sqrtf(tdn) + MARGIN;
        ws[row] = fmaxf(loss, 0.0f);
    }
}

// Stage 2: reduce B_ROWS partials -> out[0]
__global__ __launch_bounds__(256) void tl_reduce(
    const float* __restrict__ ws, float* __restrict__ out)
{
    const int tid  = threadIdx.x;
    const int lane = tid & 63;
    const int wave = tid >> 6;

    // 16384 floats = 4096 float4; 256 threads x 16 float4
    const vfloat4* w4 = (const vfloat4*)ws;
    float s = 0.0f;
    #pragma unroll
    for (int it = 0; it < 16; ++it) {
        const vfloat4 v = w4[it * 256 + tid];
        s += v.x + v.y + v.z + v.w;
    }

    #pragma unroll
    for (int off = 32; off > 0; off >>= 1) {
        s += __shfl_down(s, off);
    }

    __shared__ float partial[4];
    if (lane == 0) partial[wave] = s;
    __syncthreads();

    if (tid == 0) {
        out[0] = (partial[0] + partial[1] + partial[2] + partial[3])
                 * (1.0f / (float)B_ROWS);
    }
}

extern "C" void kernel_launch(void* const* d_in, const int* in_sizes, int n_in,
                              void* d_out, int out_size, void* d_ws, size_t ws_size,
                              hipStream_t stream) {
    const float* anc = (const float*)d_in[0];
    const float* pos = (const float*)d_in[1];
    const float* neg = (const float*)d_in[2];
    float* out = (float*)d_out;
    float* ws  = (float*)d_ws;

    TripletLoss_90091234001212_kernel<<<B_ROWS, 256, 0, stream>>>(anc, pos, neg, ws);
    tl_reduce<<<1, 256, 0, stream>>>(ws, out);
}